// Round 5
// baseline (42.829 us; speedup 1.0000x reference)
//
#include <hip/hip_runtime.h>
#include <math.h>

// Closed-form element Hessian for Neo-Hookean energy (MU=LAM=1, Q=1).
// H[a][i][b][k] = vol * ( MU*d_ik*(G[a].G[b]) + LAM*g[a][i]*g[b][k]
//                         + (MU - LAM*logJ)*g[a][k]*g[b][i] ),  g = G * Finv
//
// R1: LDS-staged coalesced output writes (fixed 3x HBM write amplification).
// R2: wave-private staging -> compile-time fences instead of __syncthreads
//     (neutral: barriers were not the cost).
// R3/R4: nontemporal stores for the 144 MB output stream and nontemporal
//     loads for read-once inputs (conns/grads/vols); L2 left to U gathers.
//     R4 fixes the compile error: nontemporal builtins need clang
//     ext_vector_type, not HIP_vector_type (float4/int4 classes).

typedef float f4 __attribute__((ext_vector_type(4)));
typedef int   i4 __attribute__((ext_vector_type(4)));

struct ElemData {
    float g[4][3];
    float dot[4][4];
    float c1, c2, c3;
};

__device__ __forceinline__ ElemData compute_elem(
    const float* __restrict__ U,
    const float* __restrict__ shape_grads,
    const float* __restrict__ vols,
    const int*  __restrict__ conns,
    size_t e)
{
    ElemData d;
    i4 cc = __builtin_nontemporal_load(
        reinterpret_cast<const i4*>(conns + e * 4));
    const f4* gp = reinterpret_cast<const f4*>(shape_grads + e * 12);
    f4 q0 = __builtin_nontemporal_load(gp + 0);
    f4 q1 = __builtin_nontemporal_load(gp + 1);
    f4 q2 = __builtin_nontemporal_load(gp + 2);
    float G[4][3];
    G[0][0]=q0[0]; G[0][1]=q0[1]; G[0][2]=q0[2];
    G[1][0]=q0[3]; G[1][1]=q1[0]; G[1][2]=q1[1];
    G[2][0]=q1[2]; G[2][1]=q1[3]; G[2][2]=q2[0];
    G[3][0]=q2[1]; G[3][1]=q2[2]; G[3][2]=q2[3];

    float vol = __builtin_nontemporal_load(vols + e);

    float F[3][3] = {{1.f,0.f,0.f},{0.f,1.f,0.f},{0.f,0.f,1.f}};
    int ca[4] = {cc[0], cc[1], cc[2], cc[3]};
    #pragma unroll
    for (int a = 0; a < 4; ++a) {
        float u0 = U[(size_t)ca[a]*3 + 0];
        float u1 = U[(size_t)ca[a]*3 + 1];
        float u2 = U[(size_t)ca[a]*3 + 2];
        #pragma unroll
        for (int j = 0; j < 3; ++j) {
            F[0][j] = fmaf(u0, G[a][j], F[0][j]);
            F[1][j] = fmaf(u1, G[a][j], F[1][j]);
            F[2][j] = fmaf(u2, G[a][j], F[2][j]);
        }
    }

    float c00 = F[1][1]*F[2][2] - F[1][2]*F[2][1];
    float c01 = F[1][2]*F[2][0] - F[1][0]*F[2][2];
    float c02 = F[1][0]*F[2][1] - F[1][1]*F[2][0];
    float det = F[0][0]*c00 + F[0][1]*c01 + F[0][2]*c02;
    float invdet = 1.0f / det;
    float logJ = logf(det);

    float Fi[3][3];
    Fi[0][0] = c00*invdet;
    Fi[1][0] = c01*invdet;
    Fi[2][0] = c02*invdet;
    Fi[0][1] = (F[0][2]*F[2][1]-F[0][1]*F[2][2])*invdet;
    Fi[1][1] = (F[0][0]*F[2][2]-F[0][2]*F[2][0])*invdet;
    Fi[2][1] = (F[0][1]*F[2][0]-F[0][0]*F[2][1])*invdet;
    Fi[0][2] = (F[0][1]*F[1][2]-F[0][2]*F[1][1])*invdet;
    Fi[1][2] = (F[0][2]*F[1][0]-F[0][0]*F[1][2])*invdet;
    Fi[2][2] = (F[0][0]*F[1][1]-F[0][1]*F[1][0])*invdet;

    #pragma unroll
    for (int a = 0; a < 4; ++a)
        #pragma unroll
        for (int i = 0; i < 3; ++i)
            d.g[a][i] = G[a][0]*Fi[0][i] + G[a][1]*Fi[1][i] + G[a][2]*Fi[2][i];

    #pragma unroll
    for (int a = 0; a < 4; ++a)
        #pragma unroll
        for (int b = 0; b < 4; ++b)
            d.dot[a][b] = G[a][0]*G[b][0] + G[a][1]*G[b][1] + G[a][2]*G[b][2];

    const float MUc = 1.0f, LAMc = 1.0f;
    d.c1 = vol * MUc;
    d.c2 = vol * LAMc;
    d.c3 = vol * (MUc - LAMc * logJ);
    return d;
}

__device__ __forceinline__ void make_row(const ElemData& d, int a, int i,
                                         f4& r0, f4& r1, f4& r2)
{
    float row[12];
    float gai = d.g[a][i];
    #pragma unroll
    for (int b = 0; b < 4; ++b) {
        #pragma unroll
        for (int k = 0; k < 3; ++k) {
            float v = d.c2 * gai * d.g[b][k] + d.c3 * d.g[a][k] * d.g[b][i];
            if (i == k) v = fmaf(d.c1, d.dot[a][b], v);
            row[b*3 + k] = v;
        }
    }
    r0 = (f4){row[0], row[1], row[2],  row[3]};
    r1 = (f4){row[4], row[5], row[6],  row[7]};
    r2 = (f4){row[8], row[9], row[10], row[11]};
}

__device__ __forceinline__ void lds_fence() {
    __builtin_amdgcn_sched_barrier(0);
    __builtin_amdgcn_wave_barrier();
    __builtin_amdgcn_sched_barrier(0);
}

__global__ __launch_bounds__(256) void mech_hess_kernel(
    const float* __restrict__ U,
    const float* __restrict__ shape_grads,
    const float* __restrict__ vols,
    const int*  __restrict__ conns,
    float* __restrict__ out,
    int E)
{
    // per-wave staging: 16 elems x 37 f4 slots (36 data + 1 pad)
    __shared__ f4 buf[4][16 * 37];

    int tid  = threadIdx.x;
    int wave = tid >> 6;
    int lane = tid & 63;
    size_t e = (size_t)blockIdx.x * 256 + tid;

    bool fullBlock = ((size_t)blockIdx.x * 256 + 256) <= (size_t)E;

    if (fullBlock) {
        ElemData d = compute_elem(U, shape_grads, vols, conns, e);
        f4* ob = reinterpret_cast<f4*>(out);

        #pragma unroll
        for (int c = 0; c < 4; ++c) {
            if ((lane >> 4) == c) {
                int m = lane & 15;
                f4* wb = &buf[wave][m * 37];
                #pragma unroll
                for (int a = 0; a < 4; ++a) {
                    #pragma unroll
                    for (int i = 0; i < 3; ++i) {
                        f4 r0, r1, r2;
                        make_row(d, a, i, r0, r1, r2);
                        int j = (a*3 + i) * 3;
                        wb[j+0] = r0; wb[j+1] = r1; wb[j+2] = r2;
                    }
                }
            }
            lds_fence();
            // coalesced write-out: 16 elems * 576B = 9216B = 576 f4
            size_t chunkF4 = ((size_t)blockIdx.x * 256 + wave*64 + c*16) * 36;
            #pragma unroll
            for (int it = 0; it < 9; ++it) {
                int s = it*64 + lane;          // 0..575
                int elem = s / 36;             // compile-time magic div
                int slot = s + elem;           // elem*37 + (s - elem*36)
                __builtin_nontemporal_store(buf[wave][slot], &ob[chunkF4 + s]);
            }
            lds_fence();
        }
    } else {
        if (e < (size_t)E) {
            ElemData d = compute_elem(U, shape_grads, vols, conns, e);
            f4* o = reinterpret_cast<f4*>(out + e * 144);
            #pragma unroll
            for (int a = 0; a < 4; ++a) {
                #pragma unroll
                for (int i = 0; i < 3; ++i) {
                    f4 r0, r1, r2;
                    make_row(d, a, i, r0, r1, r2);
                    o[(a*3+i)*3 + 0] = r0;
                    o[(a*3+i)*3 + 1] = r1;
                    o[(a*3+i)*3 + 2] = r2;
                }
            }
        }
    }
}

extern "C" void kernel_launch(void* const* d_in, const int* in_sizes, int n_in,
                              void* d_out, int out_size, void* d_ws, size_t ws_size,
                              hipStream_t stream) {
    // setup_inputs order: U, coords, state, shapes, shape_grads, vols, conns
    const float* U           = (const float*)d_in[0];
    const float* shape_grads = (const float*)d_in[4];
    const float* vols        = (const float*)d_in[5];
    const int*   conns       = (const int*)d_in[6];
    float* out = (float*)d_out;

    int E = in_sizes[5];  // vols is (E, 1)

    int block = 256;
    int grid = (E + block - 1) / block;
    mech_hess_kernel<<<grid, block, 0, stream>>>(U, shape_grads, vols, conns, out, E);
}

// Round 6
// 33.724 us; speedup vs baseline: 1.2700x; 1.2700x over previous
//
#include <hip/hip_runtime.h>
#include <math.h>

// Closed-form element Hessian for Neo-Hookean energy (MU=LAM=1, Q=1).
// H[a][i][b][k] = vol * ( MU*d_ik*(G[a].G[b]) + LAM*g[a][i]*g[b][k]
//                         + (MU - LAM*logJ)*g[a][k]*g[b][i] ),  g = G * Finv
//
// R1: LDS-staged coalesced output writes (fixed 3x HBM write amplification).
// R2: wave-private staging -> compile-time fences instead of __syncthreads (neutral).
// R3/R4: nontemporal loads/stores -> REGRESSED 26% (L2 write-combining was
//        helping). Reverted.
// R5: dense row computation. R2 ran make_row 4x per wave exec-masked at 16/64
//     lanes (~720 serial VALU cycles per phase). Now the 16 owner lanes
//     publish ElemData (31 floats) to LDS per phase; ALL 64 lanes compute
//     3 rows each (elem=lane>>2, rowgroup r=lane&3 == a). Per-phase VALU
//     ~95 instrs. Writeback mapping identical to R2.

typedef float f4 __attribute__((ext_vector_type(4)));

struct ElemData {
    float g[4][3];
    float dot[4][4];
    float c1, c2, c3;
};

__device__ __forceinline__ ElemData compute_elem(
    const float* __restrict__ U,
    const float* __restrict__ shape_grads,
    const float* __restrict__ vols,
    const int*  __restrict__ conns,
    size_t e)
{
    ElemData d;
    i4_alias:;
    const int4* cp = reinterpret_cast<const int4*>(conns + e * 4);
    int4 cc = *cp;
    const float4* gp = reinterpret_cast<const float4*>(shape_grads + e * 12);
    float4 q0 = gp[0], q1 = gp[1], q2 = gp[2];
    float G[4][3];
    G[0][0]=q0.x; G[0][1]=q0.y; G[0][2]=q0.z;
    G[1][0]=q0.w; G[1][1]=q1.x; G[1][2]=q1.y;
    G[2][0]=q1.z; G[2][1]=q1.w; G[2][2]=q2.x;
    G[3][0]=q2.y; G[3][1]=q2.z; G[3][2]=q2.w;

    float vol = vols[e];

    float F[3][3] = {{1.f,0.f,0.f},{0.f,1.f,0.f},{0.f,0.f,1.f}};
    int ca[4] = {cc.x, cc.y, cc.z, cc.w};
    #pragma unroll
    for (int a = 0; a < 4; ++a) {
        float u0 = U[(size_t)ca[a]*3 + 0];
        float u1 = U[(size_t)ca[a]*3 + 1];
        float u2 = U[(size_t)ca[a]*3 + 2];
        #pragma unroll
        for (int j = 0; j < 3; ++j) {
            F[0][j] = fmaf(u0, G[a][j], F[0][j]);
            F[1][j] = fmaf(u1, G[a][j], F[1][j]);
            F[2][j] = fmaf(u2, G[a][j], F[2][j]);
        }
    }

    float c00 = F[1][1]*F[2][2] - F[1][2]*F[2][1];
    float c01 = F[1][2]*F[2][0] - F[1][0]*F[2][2];
    float c02 = F[1][0]*F[2][1] - F[1][1]*F[2][0];
    float det = F[0][0]*c00 + F[0][1]*c01 + F[0][2]*c02;
    float invdet = 1.0f / det;
    float logJ = logf(det);

    float Fi[3][3];
    Fi[0][0] = c00*invdet;
    Fi[1][0] = c01*invdet;
    Fi[2][0] = c02*invdet;
    Fi[0][1] = (F[0][2]*F[2][1]-F[0][1]*F[2][2])*invdet;
    Fi[1][1] = (F[0][0]*F[2][2]-F[0][2]*F[2][0])*invdet;
    Fi[2][1] = (F[0][1]*F[2][0]-F[0][0]*F[2][1])*invdet;
    Fi[0][2] = (F[0][1]*F[1][2]-F[0][2]*F[1][1])*invdet;
    Fi[1][2] = (F[0][2]*F[1][0]-F[0][0]*F[1][2])*invdet;
    Fi[2][2] = (F[0][0]*F[1][1]-F[0][1]*F[1][0])*invdet;

    #pragma unroll
    for (int a = 0; a < 4; ++a)
        #pragma unroll
        for (int i = 0; i < 3; ++i)
            d.g[a][i] = G[a][0]*Fi[0][i] + G[a][1]*Fi[1][i] + G[a][2]*Fi[2][i];

    #pragma unroll
    for (int a = 0; a < 4; ++a)
        #pragma unroll
        for (int b = 0; b < 4; ++b)
            d.dot[a][b] = G[a][0]*G[b][0] + G[a][1]*G[b][1] + G[a][2]*G[b][2];

    const float MUc = 1.0f, LAMc = 1.0f;
    d.c1 = vol * MUc;
    d.c2 = vol * LAMc;
    d.c3 = vol * (MUc - LAMc * logJ);
    return d;
}

__device__ __forceinline__ void make_row(const ElemData& d, int a, int i,
                                         f4& r0, f4& r1, f4& r2)
{
    float row[12];
    float gai = d.g[a][i];
    #pragma unroll
    for (int b = 0; b < 4; ++b) {
        #pragma unroll
        for (int k = 0; k < 3; ++k) {
            float v = d.c2 * gai * d.g[b][k] + d.c3 * d.g[a][k] * d.g[b][i];
            if (i == k) v = fmaf(d.c1, d.dot[a][b], v);
            row[b*3 + k] = v;
        }
    }
    r0 = (f4){row[0], row[1], row[2],  row[3]};
    r1 = (f4){row[4], row[5], row[6],  row[7]};
    r2 = (f4){row[8], row[9], row[10], row[11]};
}

__device__ __forceinline__ void lds_fence() {
    __builtin_amdgcn_sched_barrier(0);
    __builtin_amdgcn_wave_barrier();
    __builtin_amdgcn_sched_barrier(0);
}

__global__ __launch_bounds__(256) void mech_hess_kernel(
    const float* __restrict__ U,
    const float* __restrict__ shape_grads,
    const float* __restrict__ vols,
    const int*  __restrict__ conns,
    float* __restrict__ out,
    int E)
{
    // per-wave LDS:
    //  edata: 16 elems * 36 floats (g:0-11, dot:12-27, c:28-30, pad)
    //  buf:   16 elems * 37 f4 slots (36 data + 1 pad)
    __shared__ float edata[4][16 * 36];
    __shared__ f4    buf[4][16 * 37];

    int tid  = threadIdx.x;
    int wave = tid >> 6;
    int lane = tid & 63;
    size_t e = (size_t)blockIdx.x * 256 + tid;

    bool fullBlock = ((size_t)blockIdx.x * 256 + 256) <= (size_t)E;

    if (fullBlock) {
        ElemData d = compute_elem(U, shape_grads, vols, conns, e);
        f4* ob = reinterpret_cast<f4*>(out);

        #pragma unroll
        for (int c = 0; c < 4; ++c) {
            // owner lanes publish ElemData for this phase's 16 elems
            if ((lane >> 4) == c) {
                int m = lane & 15;
                float* ed = &edata[wave][m * 36];
                f4 w0 = (f4){d.g[0][0], d.g[0][1], d.g[0][2], d.g[1][0]};
                f4 w1 = (f4){d.g[1][1], d.g[1][2], d.g[2][0], d.g[2][1]};
                f4 w2 = (f4){d.g[2][2], d.g[3][0], d.g[3][1], d.g[3][2]};
                *reinterpret_cast<f4*>(ed + 0) = w0;
                *reinterpret_cast<f4*>(ed + 4) = w1;
                *reinterpret_cast<f4*>(ed + 8) = w2;
                #pragma unroll
                for (int a = 0; a < 4; ++a) {
                    f4 wd = (f4){d.dot[a][0], d.dot[a][1], d.dot[a][2], d.dot[a][3]};
                    *reinterpret_cast<f4*>(ed + 12 + 4*a) = wd;
                }
                f4 wc = (f4){d.c1, d.c2, d.c3, 0.f};
                *reinterpret_cast<f4*>(ed + 28) = wc;
            }
            lds_fence();
            // ALL lanes: compute 3 rows for elem (lane>>2), rowgroup r = lane&3 (== a)
            {
                int el2 = lane >> 2;
                int r   = lane & 3;
                const float* ed = &edata[wave][el2 * 36];
                f4 ga = *reinterpret_cast<const f4*>(ed + 0);
                f4 gb = *reinterpret_cast<const f4*>(ed + 4);
                f4 gc = *reinterpret_cast<const f4*>(ed + 8);
                f4 dr = *reinterpret_cast<const f4*>(ed + 12 + 4*r);
                f4 cv = *reinterpret_cast<const f4*>(ed + 28);
                float g[12] = {ga[0],ga[1],ga[2],ga[3],gb[0],gb[1],gb[2],gb[3],
                               gc[0],gc[1],gc[2],gc[3]};
                float c1 = cv[0], c2 = cv[1], c3 = cv[2];
                f4* wb = &buf[wave][el2 * 37 + r * 9];
                #pragma unroll
                for (int i = 0; i < 3; ++i) {
                    float gai = g[r*3 + i];
                    float row[12];
                    #pragma unroll
                    for (int b = 0; b < 4; ++b) {
                        #pragma unroll
                        for (int k = 0; k < 3; ++k) {
                            float v = c2 * gai * g[b*3 + k] + c3 * g[r*3 + k] * g[b*3 + i];
                            if (i == k) v = fmaf(c1, dr[b], v);
                            row[b*3 + k] = v;
                        }
                    }
                    wb[i*3 + 0] = (f4){row[0], row[1], row[2],  row[3]};
                    wb[i*3 + 1] = (f4){row[4], row[5], row[6],  row[7]};
                    wb[i*3 + 2] = (f4){row[8], row[9], row[10], row[11]};
                }
            }
            lds_fence();
            // coalesced write-out: 16 elems * 576B = 576 f4
            size_t chunkF4 = ((size_t)blockIdx.x * 256 + wave*64 + c*16) * 36;
            #pragma unroll
            for (int it = 0; it < 9; ++it) {
                int s = it*64 + lane;          // 0..575
                int elem = s / 36;
                int slot = s + elem;           // elem*37 + (s - elem*36)
                ob[chunkF4 + s] = buf[wave][slot];
            }
            lds_fence();
        }
    } else {
        if (e < (size_t)E) {
            ElemData d = compute_elem(U, shape_grads, vols, conns, e);
            f4* o = reinterpret_cast<f4*>(out + e * 144);
            #pragma unroll
            for (int a = 0; a < 4; ++a) {
                #pragma unroll
                for (int i = 0; i < 3; ++i) {
                    f4 r0, r1, r2;
                    make_row(d, a, i, r0, r1, r2);
                    o[(a*3+i)*3 + 0] = r0;
                    o[(a*3+i)*3 + 1] = r1;
                    o[(a*3+i)*3 + 2] = r2;
                }
            }
        }
    }
}

extern "C" void kernel_launch(void* const* d_in, const int* in_sizes, int n_in,
                              void* d_out, int out_size, void* d_ws, size_t ws_size,
                              hipStream_t stream) {
    // setup_inputs order: U, coords, state, shapes, shape_grads, vols, conns
    const float* U           = (const float*)d_in[0];
    const float* shape_grads = (const float*)d_in[4];
    const float* vols        = (const float*)d_in[5];
    const int*   conns       = (const int*)d_in[6];
    float* out = (float*)d_out;

    int E = in_sizes[5];  // vols is (E, 1)

    int block = 256;
    int grid = (E + block - 1) / block;
    mech_hess_kernel<<<grid, block, 0, stream>>>(U, shape_grads, vols, conns, out, E);
}